// Round 1
// baseline (828.699 us; speedup 1.0000x reference)
//
#include <hip/hip_runtime.h>
#include <hip/hip_bf16.h>

// out[b,k,o,f] = entmax15( x[b,f,:] @ W2'[k,:,o] ) * values[k,o,f]
// W2'[k,x,o] = 0.0625 * sum_y bw[k,x,y] * q[k,o,y]   (scale * (alpha-1) folded in)
// b=2048, k=8, o=64, f=128, x=128, y=64

using half8_t  = __attribute__((ext_vector_type(8))) _Float16;
using half4_t  = __attribute__((ext_vector_type(4))) _Float16;
using floatx4  = __attribute__((ext_vector_type(4))) float;

#define NITER 18

// ---------------- Kernel A: W2'[k][o][x] fp16 into workspace ----------------
__global__ __launch_bounds__(256) void w2_kernel(const float* __restrict__ bw,
                                                 const float* __restrict__ qm,
                                                 _Float16* __restrict__ W2h) {
    const int k  = blockIdx.x >> 3;
    const int og = blockIdx.x & 7;          // o-chunk of 8 rows
    __shared__ float Lbw[128 * 65];         // [x][y] padded (+1) -> conflict-free
    __shared__ float Lq[8 * 64];            // [o][y]
    const int t = threadIdx.x;

    const float* bwk = bw + k * 8192;       // [128][64]
    #pragma unroll
    for (int i2 = 0; i2 < 8; ++i2) {
        int i = t + i2 * 256;               // float4 index, 2048 total
        float4 v = ((const float4*)bwk)[i];
        int xx = (i * 4) >> 6, y = (i * 4) & 63;
        float* dst = &Lbw[xx * 65 + y];
        dst[0] = v.x; dst[1] = v.y; dst[2] = v.z; dst[3] = v.w;
    }
    const float* qk = qm + k * 4096 + og * 8 * 64;
    if (t < 128) ((float4*)Lq)[t] = ((const float4*)qk)[t];
    __syncthreads();

    #pragma unroll
    for (int i = 0; i < 4; ++i) {
        int ox = i * 256 + t;               // 1024 outputs: [8 o][128 x]
        int o = ox >> 7, x = ox & 127;
        const float* brow = &Lbw[x * 65];
        const float* qrow = &Lq[o * 64];
        float acc = 0.f;
        #pragma unroll
        for (int y = 0; y < 64; ++y) acc = fmaf(brow[y], qrow[y], acc);
        W2h[(k * 64 + og * 8 + o) * 128 + x] = (_Float16)(acc * 0.0625f);
    }
}

// ---------------- Kernel B: fused GEMM + entmax + scale ----------------
// block = one (b,k); 256 threads = 4 waves; wave w owns o in [16w,16w+16)
__global__ __launch_bounds__(256, 3) void satt_kernel(
        const float* __restrict__ xg, const _Float16* __restrict__ W2h,
        const float* __restrict__ values, float* __restrict__ out) {
    const int bid = blockIdx.x;
    const int b = bid >> 3, k = bid & 7;
    const int t = threadIdx.x;
    const int w = t >> 6, l = t & 63;

    // union: {Ash[64][136] fp16 (17408B) + Bsh[128][136] fp16 (34816B)} / zsh[64][132] f32 (33792B)
    __shared__ __align__(16) char smem[52224];
    _Float16* Ash = (_Float16*)smem;
    _Float16* Bsh = (_Float16*)(smem + 17408);
    float*    zsh = (float*)smem;

    // Stage A: W2'[k] = [64 o][128 x] fp16 (16 KB), 1024 x 16B chunks
    const _Float16* w2k = W2h + k * 8192;
    #pragma unroll
    for (int j = 0; j < 4; ++j) {
        int c = t + 256 * j;
        int o = c >> 4, x0 = (c & 15) * 8;
        uint4 v = ((const uint4*)w2k)[c];
        *(uint4*)(Ash + o * 136 + x0) = v;
    }
    // Stage B: x[b] = [128 f][128 x] fp32 -> fp16 LDS
    const float* xb = xg + (size_t)b * 16384;
    #pragma unroll
    for (int j = 0; j < 16; ++j) {
        int c = t + 256 * j;                // float4 index, 4096 total
        int f = c >> 5, x0 = (c & 31) * 4;
        float4 v = ((const float4*)xb)[c];
        half4_t h;
        h[0] = (_Float16)v.x; h[1] = (_Float16)v.y;
        h[2] = (_Float16)v.z; h[3] = (_Float16)v.w;
        *(half4_t*)(Bsh + f * 136 + x0) = h;
    }
    __syncthreads();

    // MFMA: z[o,f] = A[o,x] * B[x,f];  A-frag: m=l&15, k=(l>>4)*8+j ; B-frag: n=l&15
    const int q = l >> 4, c16 = l & 15;
    half8_t afrag[4];
    #pragma unroll
    for (int kk = 0; kk < 4; ++kk)
        afrag[kk] = *(const half8_t*)(Ash + (w * 16 + c16) * 136 + kk * 32 + q * 8);

    floatx4 acc[8];
    #pragma unroll
    for (int ft = 0; ft < 8; ++ft) acc[ft] = (floatx4){0.f, 0.f, 0.f, 0.f};

    #pragma unroll
    for (int kk = 0; kk < 4; ++kk) {
        #pragma unroll
        for (int ft = 0; ft < 8; ++ft) {
            half8_t bfrag = *(const half8_t*)(Bsh + (ft * 16 + c16) * 136 + kk * 32 + q * 8);
            acc[ft] = __builtin_amdgcn_mfma_f32_16x16x32_f16(afrag[kk], bfrag, acc[ft], 0, 0, 0);
        }
    }
    __syncthreads();   // all MFMA LDS reads done before aliasing as zsh

    // C layout: n(f) = ft*16 + (l&15), m(o) = w*16 + q*4 + r  -> zsh[o][f], stride 132
    #pragma unroll
    for (int ft = 0; ft < 8; ++ft) {
        #pragma unroll
        for (int r = 0; r < 4; ++r)
            zsh[(w * 16 + q * 4 + r) * 132 + ft * 16 + c16] = acc[ft][r];
    }
    __syncthreads();

    // Entmax-1.5 bisection: lane owns row o = w*16 + (l>>2), f in [32s, 32s+32)
    const int row = l >> 2, s = l & 3;
    const int o = w * 16 + row;
    float zz[32];
    #pragma unroll
    for (int j = 0; j < 8; ++j) {
        floatx4 v = *(const floatx4*)(zsh + o * 132 + s * 32 + j * 4);
        zz[4 * j + 0] = v[0]; zz[4 * j + 1] = v[1];
        zz[4 * j + 2] = v[2]; zz[4 * j + 3] = v[3];
    }
    float m = zz[0];
    #pragma unroll
    for (int j = 1; j < 32; ++j) m = fmaxf(m, zz[j]);
    m = fmaxf(m, __shfl_xor(m, 1));
    m = fmaxf(m, __shfl_xor(m, 2));

    float tau = m - 1.0f;
    float dm  = 0.9116116523516816f;        // 1 - (1/128)^0.5
    float ssum = 0.f;
    #pragma unroll
    for (int j = 0; j < 32; ++j) { float d = fmaxf(zz[j] - tau, 0.f); ssum = fmaf(d, d, ssum); }
    ssum += __shfl_xor(ssum, 1); ssum += __shfl_xor(ssum, 2);
    const float f_lo = ssum - 1.0f;

    for (int it = 0; it < NITER; ++it) {
        dm *= 0.5f;
        float tm = tau + dm;
        float sa = 0.f;
        #pragma unroll
        for (int j = 0; j < 32; ++j) { float d = fmaxf(zz[j] - tm, 0.f); sa = fmaf(d, d, sa); }
        sa += __shfl_xor(sa, 1); sa += __shfl_xor(sa, 2);
        float fm = sa - 1.0f;
        tau = (fm * f_lo >= 0.f) ? tm : tau;
    }
    const float te = tau + dm;
    float ps = 0.f;
    #pragma unroll
    for (int j = 0; j < 32; ++j) {
        float d = fmaxf(zz[j] - te, 0.f);
        float p = d * d;
        zz[j] = p;
        ps += p;
    }
    ps += __shfl_xor(ps, 1); ps += __shfl_xor(ps, 2);
    const float inv = 1.0f / ps;

    const float* vrow = values + ((k * 64 + o) * 128 + s * 32);
    float* orow = out + ((((size_t)b * 8 + k) * 64 + o) * 128 + s * 32);
    #pragma unroll
    for (int j = 0; j < 8; ++j) {
        floatx4 vv = *(const floatx4*)(vrow + 4 * j);
        floatx4 g;
        g[0] = zz[4 * j + 0] * inv * vv[0];
        g[1] = zz[4 * j + 1] * inv * vv[1];
        g[2] = zz[4 * j + 2] * inv * vv[2];
        g[3] = zz[4 * j + 3] * inv * vv[3];
        *(floatx4*)(orow + 4 * j) = g;
    }
}

extern "C" void kernel_launch(void* const* d_in, const int* in_sizes, int n_in,
                              void* d_out, int out_size, void* d_ws, size_t ws_size,
                              hipStream_t stream) {
    const float* xg     = (const float*)d_in[0];   // [2048,128,128]
    const float* bw     = (const float*)d_in[1];   // [8,128,64]
    const float* qm     = (const float*)d_in[2];   // [8,64,64]
    const float* values = (const float*)d_in[3];   // [8,64,128]
    float* out = (float*)d_out;                    // [2048,8,64,128]
    _Float16* W2h = (_Float16*)d_ws;               // 65536 halves = 128 KB

    w2_kernel<<<64, 256, 0, stream>>>(bw, qm, W2h);
    satt_kernel<<<16384, 256, 0, stream>>>(xg, W2h, values, out);
}